// Round 15
// baseline (1297.039 us; speedup 1.0000x reference)
//
#include <hip/hip_runtime.h>
#include <hip/hip_cooperative_groups.h>
#include <math.h>

namespace cg = cooperative_groups;

#define NEG_SLOPE 0.2f
#define ECLAMP 80.0f
#define BUCKET_SHIFT 7      // 128 nodes per bucket
#define BUCKET_MASK 127
#define NPB 128
#define NBMAX 1024
#define SC 2048             // scan chunk (256 thr * 8)
#define EB_CHUNK 2048       // fallback: edges per partition block
#define P4_MAXIT 16         // fallback: register-captured edges/thread

__device__ __forceinline__ float lrelu(float e) {
    return e > 0.f ? e : NEG_SLOPE * e;
}

// ===================== Cooperative mega-kernel (8 phases) ====================
__global__ __launch_bounds__(256, 4)
void gat_mega(const float* __restrict__ x,
              const int* __restrict__ srcp, const int* __restrict__ dstp,
              const float* __restrict__ W1, const float* __restrict__ a_src1,
              const float* __restrict__ a_dst1, const float* __restrict__ b1,
              const float* __restrict__ W2, const float* __restrict__ a_src2,
              const float* __restrict__ a_dst2, const float* __restrict__ b2,
              float* __restrict__ out,
              float* __restrict__ as1, float* __restrict__ ad1,
              float* __restrict__ ad2, float4* __restrict__ h2p,
              int* __restrict__ rp, int* __restrict__ cmatT,
              int* __restrict__ cscan, int* __restrict__ bsum,
              int* __restrict__ bscan, unsigned int* __restrict__ ebuf,
              int* __restrict__ esrt,
              int N, int E, int NB, int nch2, int chunkE)
{
    cg::grid_group grid = cg::this_grid();
    const int tid = threadIdx.x, bid = blockIdx.x, G = gridDim.x;
    const int gid = bid * 256 + tid;
    const int gstep = G * 256;
    const int lane = tid & 63, wid = tid >> 6;
    const int M = NB * G;
    __shared__ int cnt[NBMAX];
    __shared__ int degl[NPB], curl[NPB];
    __shared__ int wsum[4];

    // Phase 1a: node prep (as1, ad1)
    const int N32 = N * 32;
    for (int t = gid; t < N32; t += gstep) {
        int n = t >> 5, c = t & 31;
        float4 xv = reinterpret_cast<const float4*>(x)[n];
        float h = xv.x * W1[c] + xv.y * W1[32 + c] + xv.z * W1[64 + c] + xv.w * W1[96 + c];
        float ts = h * a_src1[c];
        float td = h * a_dst1[c];
#pragma unroll
        for (int m = 8; m >= 1; m >>= 1) {
            ts += __shfl_xor(ts, m);
            td += __shfl_xor(td, m);
        }
        if ((c & 15) == 0) {
            int hh = c >> 4;
            as1[n * 2 + hh] = ts;
            ad1[n * 2 + hh] = td;
        }
    }
    // Phase 1b: bucket histogram (one chunk per block)
    for (int b = tid; b < NB; b += 256) cnt[b] = 0;
    __syncthreads();
    {
        int base = bid * chunkE;
        int end = min(base + chunkE, E);
        for (int e = base + tid; e < end; e += 256)
            atomicAdd(&cnt[dstp[e] >> BUCKET_SHIFT], 1);
    }
    __syncthreads();
    for (int b = tid; b < NB; b += 256)
        cmatT[(size_t)b * G + bid] = cnt[b];
    __threadfence();
    grid.sync();

    // Phase 2: scan partial sums
    for (int chunk = bid; chunk < nch2; chunk += G) {
        int base = chunk * SC + tid * 8;
        int lsum = 0;
#pragma unroll
        for (int i = 0; i < 8; ++i) {
            int idx = base + i;
            lsum += (idx < M) ? cmatT[idx] : 0;
        }
#pragma unroll
        for (int m = 32; m >= 1; m >>= 1) lsum += __shfl_xor(lsum, m);
        if (lane == 0) wsum[wid] = lsum;
        __syncthreads();
        if (tid == 0) bsum[chunk] = wsum[0] + wsum[1] + wsum[2] + wsum[3];
        __syncthreads();
    }
    __threadfence();
    grid.sync();

    // Phase 3: exclusive scan of partials (block 0)
    if (bid == 0) {
        int carry = 0;
        for (int base = 0; base < nch2; base += 256) {
            int i = base + tid;
            int v = (i < nch2) ? bsum[i] : 0;
            int xx = v;
#pragma unroll
            for (int off = 1; off < 64; off <<= 1) {
                int t = __shfl_up(xx, off);
                if (lane >= off) xx += t;
            }
            if (lane == 63) wsum[wid] = xx;
            __syncthreads();
            int woff = 0;
            for (int w = 0; w < wid; ++w) woff += wsum[w];
            if (i < nch2) bscan[i] = carry + woff + xx - v;
            carry += wsum[0] + wsum[1] + wsum[2] + wsum[3];
            __syncthreads();
        }
    }
    __threadfence();
    grid.sync();

    // Phase 4: rescan -> cscan
    for (int chunk = bid; chunk < nch2; chunk += G) {
        int base = chunk * SC + tid * 8;
        int v[8], pre[8];
        int lsum = 0;
#pragma unroll
        for (int i = 0; i < 8; ++i) {
            int idx = base + i;
            v[i] = (idx < M) ? cmatT[idx] : 0;
            pre[i] = lsum;
            lsum += v[i];
        }
        int xs = lsum;
#pragma unroll
        for (int off = 1; off < 64; off <<= 1) {
            int t = __shfl_up(xs, off);
            if (lane >= off) xs += t;
        }
        if (lane == 63) wsum[wid] = xs;
        __syncthreads();
        int woff = 0;
        for (int w = 0; w < wid; ++w) woff += wsum[w];
        int off0 = bscan[chunk] + woff + xs - lsum;
#pragma unroll
        for (int i = 0; i < 8; ++i) {
            int idx = base + i;
            if (idx < M) cscan[idx] = off0 + pre[i];
        }
        __syncthreads();
    }
    __threadfence();
    grid.sync();

    // Phase 5: scatter edges -> ebuf
    for (int b = tid; b < NB; b += 256)
        cnt[b] = cscan[(size_t)b * G + bid];
    __syncthreads();
    {
        int base = bid * chunkE;
        int end = min(base + chunkE, E);
        for (int e = base + tid; e < end; e += 256) {
            int d = dstp[e];
            int bb = d >> BUCKET_SHIFT;
            int pos = atomicAdd(&cnt[bb], 1);
            ebuf[pos] = (unsigned int)srcp[e] | ((unsigned int)(d & BUCKET_MASK) << 24);
        }
    }
    __threadfence();
    grid.sync();

    // Phase 6: per-bucket CSR finalize (rp, esrt)
    if (bid == 0 && tid == 0) rp[N] = E;
    for (int b = bid; b < NB; b += G) {
        int bstart = cscan[(size_t)b * G];
        int bend = (b + 1 < NB) ? cscan[(size_t)(b + 1) * G] : E;
        int cntE = bend - bstart;
        if (tid < NPB) degl[tid] = 0;
        __syncthreads();
        for (int i = tid; i < cntE; i += 256)
            atomicAdd(&degl[ebuf[bstart + i] >> 24], 1);
        __syncthreads();
        int v = (tid < NPB) ? degl[tid] : 0;
        int xs = v;
#pragma unroll
        for (int off = 1; off < 64; off <<= 1) {
            int t = __shfl_up(xs, off);
            if (lane >= off) xs += t;
        }
        if (lane == 63) wsum[wid] = xs;
        __syncthreads();
        int woff = 0;
        for (int w = 0; w < wid; ++w) woff += wsum[w];
        int excl = woff + xs - v;
        int node = (b << BUCKET_SHIFT) + tid;
        if (tid < NPB) {
            if (node < N) rp[node] = bstart + excl;
            curl[tid] = bstart + excl;
        }
        __syncthreads();
        for (int i = tid; i < cntE; i += 256) {
            unsigned int ev = ebuf[bstart + i];
            int pos = atomicAdd(&curl[ev >> 24], 1);
            esrt[pos] = (int)(ev & 0x00FFFFFFu);
        }
        __syncthreads();
    }
    __threadfence();
    grid.sync();

    // Phase 7: layer-1 aggregate (x-space) + fused epilogue
    const float2* as1v = reinterpret_cast<const float2*>(as1);
    const float2* ad1v = reinterpret_cast<const float2*>(ad1);
    const float4* x4 = reinterpret_cast<const float4*>(x);
    const int N8 = N * 8;
    for (int t = gid; t < N8; t += gstep) {
        int n = t >> 3, j = t & 7;
        float2 adv = ad1v[n];
        float s0 = 0.f, s1 = 0.f;
        float g00 = 0.f, g01 = 0.f, g02 = 0.f, g03 = 0.f;
        float g10 = 0.f, g11 = 0.f, g12 = 0.f, g13 = 0.f;
        if (j == 0) {
            float2 av = as1v[n];
            float4 xv = x4[n];
            float w0 = __expf(fminf(lrelu(av.x + adv.x), ECLAMP));
            float w1 = __expf(fminf(lrelu(av.y + adv.y), ECLAMP));
            s0 = w0; s1 = w1;
            g00 = w0 * xv.x; g01 = w0 * xv.y; g02 = w0 * xv.z; g03 = w0 * xv.w;
            g10 = w1 * xv.x; g11 = w1 * xv.y; g12 = w1 * xv.z; g13 = w1 * xv.w;
        }
        int p0 = rp[n], p1 = rp[n + 1];
        for (int p = p0 + j; p < p1; p += 8) {
            int sn = esrt[p];
            float2 av = as1v[sn];
            float4 xv = x4[sn];
            float w0 = __expf(fminf(lrelu(av.x + adv.x), ECLAMP));
            float w1 = __expf(fminf(lrelu(av.y + adv.y), ECLAMP));
            s0 += w0; s1 += w1;
            g00 += w0 * xv.x; g01 += w0 * xv.y; g02 += w0 * xv.z; g03 += w0 * xv.w;
            g10 += w1 * xv.x; g11 += w1 * xv.y; g12 += w1 * xv.z; g13 += w1 * xv.w;
        }
#pragma unroll
        for (int msk = 1; msk <= 4; msk <<= 1) {
            s0 += __shfl_xor(s0, msk);   s1 += __shfl_xor(s1, msk);
            g00 += __shfl_xor(g00, msk); g01 += __shfl_xor(g01, msk);
            g02 += __shfl_xor(g02, msk); g03 += __shfl_xor(g03, msk);
            g10 += __shfl_xor(g10, msk); g11 += __shfl_xor(g11, msk);
            g12 += __shfl_xor(g12, msk); g13 += __shfl_xor(g13, msk);
        }
        float r0 = 1.f / s0, r1 = 1.f / s1;
        bool h1sel = (j >= 4);
        float ax = h1sel ? g10 * r1 : g00 * r0;
        float ay = h1sel ? g11 * r1 : g01 * r0;
        float az = h1sel ? g12 * r1 : g02 * r0;
        float aw = h1sel ? g13 * r1 : g03 * r0;
        float t0 = 0.f, t1 = 0.f;
#pragma unroll
        for (int jj = 0; jj < 4; ++jj) {
            int c = j * 4 + jj;
            float o = b1[c] + ax * W1[c] + ay * W1[32 + c]
                    + az * W1[64 + c] + aw * W1[96 + c];
            o = o > 0.f ? o : expm1f(o);
            t0 += o * W2[c * 2 + 0];
            t1 += o * W2[c * 2 + 1];
        }
#pragma unroll
        for (int msk = 1; msk <= 4; msk <<= 1) {
            t0 += __shfl_xor(t0, msk);
            t1 += __shfl_xor(t1, msk);
        }
        if (j == 0) {
            float as2v = t0 * a_src2[0] + t1 * a_src2[1];
            float ad2v = t0 * a_dst2[0] + t1 * a_dst2[1];
            h2p[n] = make_float4(t0, t1, as2v, 0.f);
            ad2[n] = ad2v;
        }
    }
    __threadfence();
    grid.sync();

    // Phase 8: layer-2 aggregate -> out
    for (int t = gid; t < N8; t += gstep) {
        int n = t >> 3, sub = t & 7;
        float ad = ad2[n];
        float s = 0.f, xx = 0.f, yy = 0.f;
        if (sub == 0) {
            float4 hv = h2p[n];
            float w = __expf(fminf(lrelu(hv.z + ad), ECLAMP));
            s = w; xx = w * hv.x; yy = w * hv.y;
        }
        int p0 = rp[n], p1 = rp[n + 1];
        for (int p = p0 + sub; p < p1; p += 8) {
            int sn = esrt[p];
            float4 hv = h2p[sn];
            float w = __expf(fminf(lrelu(hv.z + ad), ECLAMP));
            s += w; xx += w * hv.x; yy += w * hv.y;
        }
#pragma unroll
        for (int msk = 1; msk <= 4; msk <<= 1) {
            s  += __shfl_xor(s, msk);
            xx += __shfl_xor(xx, msk);
            yy += __shfl_xor(yy, msk);
        }
        if (sub == 0) {
            float2 o;
            o.x = xx / s + b2[0];
            o.y = yy / s + b2[1];
            reinterpret_cast<float2*>(out)[n] = o;
        }
    }
}

// ===================== Fallback pipeline (round-13, measured) ================
__global__ void k0_prep1(const float* __restrict__ x, const float* __restrict__ W1,
                         const float* __restrict__ a_src1, const float* __restrict__ a_dst1,
                         float* __restrict__ as1, float* __restrict__ ad1, int N) {
    int t = blockIdx.x * blockDim.x + threadIdx.x;
    int n = t >> 5, c = t & 31;
    if (n >= N) return;
    const float4 xv = reinterpret_cast<const float4*>(x)[n];
    float h = xv.x * W1[c] + xv.y * W1[32 + c] + xv.z * W1[64 + c] + xv.w * W1[96 + c];
    float ts = h * a_src1[c];
    float td = h * a_dst1[c];
#pragma unroll
    for (int m = 8; m >= 1; m >>= 1) {
        ts += __shfl_xor(ts, m);
        td += __shfl_xor(td, m);
    }
    if ((c & 15) == 0) {
        int hh = c >> 4;
        as1[n * 2 + hh] = ts;
        ad1[n * 2 + hh] = td;
    }
}

__global__ void p1_hist(const int* __restrict__ dst, int* __restrict__ cmatT,
                        int E, int NB, int nblkE) {
    __shared__ int cnt[NBMAX];
    const int blk = blockIdx.x, tid = threadIdx.x;
    for (int b = tid; b < NB; b += 256) cnt[b] = 0;
    __syncthreads();
    int base = blk * EB_CHUNK;
    int end = min(base + EB_CHUNK, E);
    for (int e = base + tid; e < end; e += 256)
        atomicAdd(&cnt[dst[e] >> BUCKET_SHIFT], 1);
    __syncthreads();
    for (int b = tid; b < NB; b += 256)
        cmatT[(size_t)b * nblkE + blk] = cnt[b];
}

__global__ void k2a_partials(const int* __restrict__ in, int* __restrict__ bsum, int n) {
    __shared__ int ws[4];
    const int tid = threadIdx.x;
    const int lane = tid & 63, wid = tid >> 6;
    int base = blockIdx.x * SC + tid * 8;
    int lsum = 0;
#pragma unroll
    for (int i = 0; i < 8; ++i) {
        int idx = base + i;
        lsum += (idx < n) ? in[idx] : 0;
    }
#pragma unroll
    for (int m = 32; m >= 1; m >>= 1) lsum += __shfl_xor(lsum, m);
    if (lane == 0) ws[wid] = lsum;
    __syncthreads();
    if (tid == 0) bsum[blockIdx.x] = ws[0] + ws[1] + ws[2] + ws[3];
}

__global__ void k2b_scanb(const int* __restrict__ bsum, int* __restrict__ bscan, int nb) {
    __shared__ int wsum[16];
    const int tid = threadIdx.x;
    const int lane = tid & 63, wid = tid >> 6;
    int carry = 0;
    for (int base = 0; base < nb; base += 1024) {
        int i = base + tid;
        int v = (i < nb) ? bsum[i] : 0;
        int xx = v;
#pragma unroll
        for (int off = 1; off < 64; off <<= 1) {
            int t = __shfl_up(xx, off);
            if (lane >= off) xx += t;
        }
        if (lane == 63) wsum[wid] = xx;
        __syncthreads();
        int woff = 0;
        for (int w = 0; w < wid; ++w) woff += wsum[w];
        if (i < nb) bscan[i] = carry + woff + xx - v;
        int tot = 0;
        for (int w = 0; w < 16; ++w) tot += wsum[w];
        carry += tot;
        __syncthreads();
    }
}

__global__ void k2c_scan(const int* __restrict__ in, const int* __restrict__ bscan,
                         int* __restrict__ out, int n) {
    __shared__ int ws[4];
    const int tid = threadIdx.x;
    const int lane = tid & 63, wid = tid >> 6;
    int base = blockIdx.x * SC + tid * 8;
    int v[8], pre[8];
    int lsum = 0;
#pragma unroll
    for (int i = 0; i < 8; ++i) {
        int idx = base + i;
        v[i] = (idx < n) ? in[idx] : 0;
        pre[i] = lsum;
        lsum += v[i];
    }
    int xs = lsum;
#pragma unroll
    for (int off = 1; off < 64; off <<= 1) {
        int t = __shfl_up(xs, off);
        if (lane >= off) xs += t;
    }
    if (lane == 63) ws[wid] = xs;
    __syncthreads();
    int woff = 0;
    for (int w = 0; w < wid; ++w) woff += ws[w];
    int off0 = bscan[blockIdx.x] + woff + xs - lsum;
#pragma unroll
    for (int i = 0; i < 8; ++i) {
        int idx = base + i;
        if (idx < n) out[idx] = off0 + pre[i];
    }
}

__global__ void p3_scatter(const int* __restrict__ src, const int* __restrict__ dst,
                           const int* __restrict__ cscan, unsigned int* __restrict__ ebuf,
                           int E, int NB, int nblkE) {
    __shared__ int cur[NBMAX];
    const int blk = blockIdx.x, tid = threadIdx.x;
    for (int b = tid; b < NB; b += 256)
        cur[b] = cscan[(size_t)b * nblkE + blk];
    __syncthreads();
    int base = blk * EB_CHUNK;
    int end = min(base + EB_CHUNK, E);
    for (int e = base + tid; e < end; e += 256) {
        int d = dst[e];
        int b = d >> BUCKET_SHIFT;
        int pos = atomicAdd(&cur[b], 1);
        ebuf[pos] = (unsigned int)src[e] | ((unsigned int)(d & BUCKET_MASK) << 24);
    }
}

__global__ void p4_csr(const unsigned int* __restrict__ ebuf,
                       const int* __restrict__ cscan,
                       int* __restrict__ rp, int* __restrict__ esrt,
                       int N, int E, int NB, int nblkE) {
    __shared__ int degl[NPB];
    __shared__ int base_[NPB];
    __shared__ int curl[NPB];
    __shared__ int wsum[4];
    const int b = blockIdx.x, tid = threadIdx.x;
    const int lane = tid & 63, wid = tid >> 6;
    int bstart = cscan[(size_t)b * nblkE];
    int bend = (b + 1 < NB) ? cscan[(size_t)(b + 1) * nblkE] : E;
    int cnt = bend - bstart;
    if (tid < NPB) degl[tid] = 0;
    __syncthreads();
    unsigned int evs[P4_MAXIT];
    int rks[P4_MAXIT];
#pragma unroll
    for (int it = 0; it < P4_MAXIT; ++it) {
        int i = it * 256 + tid;
        if (i < cnt) {
            unsigned int ev = ebuf[bstart + i];
            evs[it] = ev;
            rks[it] = atomicAdd(&degl[ev >> 24], 1);
        }
    }
    for (int i = P4_MAXIT * 256 + tid; i < cnt; i += 256)
        atomicAdd(&degl[ebuf[bstart + i] >> 24], 1);
    __syncthreads();
    int v = (tid < NPB) ? degl[tid] : 0;
    int xs = v;
#pragma unroll
    for (int off = 1; off < 64; off <<= 1) {
        int t = __shfl_up(xs, off);
        if (lane >= off) xs += t;
    }
    if (lane == 63) wsum[wid] = xs;
    __syncthreads();
    int woff = 0;
    for (int w = 0; w < wid; ++w) woff += wsum[w];
    int excl = woff + xs - v;
    int node = (b << BUCKET_SHIFT) + tid;
    if (tid < NPB) {
        if (node < N) rp[node] = bstart + excl;
        base_[tid] = bstart + excl;
    }
    if (b == 0 && tid == 0) rp[N] = E;
    __syncthreads();
    if (cnt <= P4_MAXIT * 256) {
#pragma unroll
        for (int it = 0; it < P4_MAXIT; ++it) {
            int i = it * 256 + tid;
            if (i < cnt) {
                unsigned int ev = evs[it];
                esrt[base_[ev >> 24] + rks[it]] = (int)(ev & 0x00FFFFFFu);
            }
        }
    } else {
        if (tid < NPB) curl[tid] = base_[tid];
        __syncthreads();
        for (int i = tid; i < cnt; i += 256) {
            unsigned int ev = ebuf[bstart + i];
            int pos = atomicAdd(&curl[ev >> 24], 1);
            esrt[pos] = (int)(ev & 0x00FFFFFFu);
        }
    }
}

__global__ void k4_layer1(const int* __restrict__ rp, const int* __restrict__ esrt,
                          const float* __restrict__ x, const float* __restrict__ as1,
                          const float* __restrict__ ad1, const float* __restrict__ b1,
                          const float* __restrict__ W1,
                          const float* __restrict__ W2, const float* __restrict__ a_src2,
                          const float* __restrict__ a_dst2,
                          float4* __restrict__ h2p, float* __restrict__ ad2, int N) {
    int t = blockIdx.x * blockDim.x + threadIdx.x;
    int n = t >> 3, j = t & 7;
    if (n >= N) return;
    const float2* as1v = reinterpret_cast<const float2*>(as1);
    const float2* ad1v = reinterpret_cast<const float2*>(ad1);
    const float4* x4 = reinterpret_cast<const float4*>(x);
    float2 adv = ad1v[n];
    float s0 = 0.f, s1 = 0.f;
    float g00 = 0.f, g01 = 0.f, g02 = 0.f, g03 = 0.f;
    float g10 = 0.f, g11 = 0.f, g12 = 0.f, g13 = 0.f;
    if (j == 0) {
        float2 av = as1v[n];
        float4 xv = x4[n];
        float w0 = __expf(fminf(lrelu(av.x + adv.x), ECLAMP));
        float w1 = __expf(fminf(lrelu(av.y + adv.y), ECLAMP));
        s0 = w0; s1 = w1;
        g00 = w0 * xv.x; g01 = w0 * xv.y; g02 = w0 * xv.z; g03 = w0 * xv.w;
        g10 = w1 * xv.x; g11 = w1 * xv.y; g12 = w1 * xv.z; g13 = w1 * xv.w;
    }
    int p0 = rp[n], p1 = rp[n + 1];
    for (int p = p0 + j; p < p1; p += 8) {
        int sn = esrt[p];
        float2 av = as1v[sn];
        float4 xv = x4[sn];
        float w0 = __expf(fminf(lrelu(av.x + adv.x), ECLAMP));
        float w1 = __expf(fminf(lrelu(av.y + adv.y), ECLAMP));
        s0 += w0; s1 += w1;
        g00 += w0 * xv.x; g01 += w0 * xv.y; g02 += w0 * xv.z; g03 += w0 * xv.w;
        g10 += w1 * xv.x; g11 += w1 * xv.y; g12 += w1 * xv.z; g13 += w1 * xv.w;
    }
#pragma unroll
    for (int msk = 1; msk <= 4; msk <<= 1) {
        s0 += __shfl_xor(s0, msk);   s1 += __shfl_xor(s1, msk);
        g00 += __shfl_xor(g00, msk); g01 += __shfl_xor(g01, msk);
        g02 += __shfl_xor(g02, msk); g03 += __shfl_xor(g03, msk);
        g10 += __shfl_xor(g10, msk); g11 += __shfl_xor(g11, msk);
        g12 += __shfl_xor(g12, msk); g13 += __shfl_xor(g13, msk);
    }
    float r0 = 1.f / s0, r1 = 1.f / s1;
    bool h1sel = (j >= 4);
    float ax = h1sel ? g10 * r1 : g00 * r0;
    float ay = h1sel ? g11 * r1 : g01 * r0;
    float az = h1sel ? g12 * r1 : g02 * r0;
    float aw = h1sel ? g13 * r1 : g03 * r0;
    float t0 = 0.f, t1 = 0.f;
#pragma unroll
    for (int jj = 0; jj < 4; ++jj) {
        int c = j * 4 + jj;
        float o = b1[c] + ax * W1[c] + ay * W1[32 + c]
                + az * W1[64 + c] + aw * W1[96 + c];
        o = o > 0.f ? o : expm1f(o);
        t0 += o * W2[c * 2 + 0];
        t1 += o * W2[c * 2 + 1];
    }
#pragma unroll
    for (int msk = 1; msk <= 4; msk <<= 1) {
        t0 += __shfl_xor(t0, msk);
        t1 += __shfl_xor(t1, msk);
    }
    if (j == 0) {
        float as2v = t0 * a_src2[0] + t1 * a_src2[1];
        float ad2v = t0 * a_dst2[0] + t1 * a_dst2[1];
        h2p[n] = make_float4(t0, t1, as2v, 0.f);
        ad2[n] = ad2v;
    }
}

__global__ void k5_layer2(const int* __restrict__ rp, const int* __restrict__ esrt,
                          const float4* __restrict__ h2p, const float* __restrict__ ad2,
                          const float* __restrict__ b2, float* __restrict__ out, int N) {
    int t = blockIdx.x * blockDim.x + threadIdx.x;
    int n = t >> 3, sub = t & 7;
    if (n >= N) return;
    float ad = ad2[n];
    float s = 0.f, xx = 0.f, yy = 0.f;
    if (sub == 0) {
        float4 hv = h2p[n];
        float w = __expf(fminf(lrelu(hv.z + ad), ECLAMP));
        s = w; xx = w * hv.x; yy = w * hv.y;
    }
    int p0 = rp[n], p1 = rp[n + 1];
    for (int p = p0 + sub; p < p1; p += 8) {
        int sn = esrt[p];
        float4 hv = h2p[sn];
        float w = __expf(fminf(lrelu(hv.z + ad), ECLAMP));
        s += w; xx += w * hv.x; yy += w * hv.y;
    }
#pragma unroll
    for (int msk = 1; msk <= 4; msk <<= 1) {
        s  += __shfl_xor(s, msk);
        xx += __shfl_xor(xx, msk);
        yy += __shfl_xor(yy, msk);
    }
    if (sub == 0) {
        float2 o;
        o.x = xx / s + b2[0];
        o.y = yy / s + b2[1];
        reinterpret_cast<float2*>(out)[n] = o;
    }
}

// ===================== launcher ==============================================
extern "C" void kernel_launch(void* const* d_in, const int* in_sizes, int n_in,
                              void* d_out, int out_size, void* d_ws, size_t ws_size,
                              hipStream_t stream) {
    const float* x      = (const float*)d_in[0];
    const int*   ei     = (const int*)d_in[1];
    const float* W1     = (const float*)d_in[2];
    const float* a_src1 = (const float*)d_in[3];
    const float* a_dst1 = (const float*)d_in[4];
    const float* b1     = (const float*)d_in[5];
    const float* W2     = (const float*)d_in[6];
    const float* a_src2 = (const float*)d_in[7];
    const float* a_dst2 = (const float*)d_in[8];
    const float* b2     = (const float*)d_in[9];
    float* out = (float*)d_out;

    int N = in_sizes[0] / 4;
    int E = in_sizes[1] / 2;
    const int* srcp = ei;
    const int* dstp = ei + E;
    int NB = (N + BUCKET_MASK) >> BUCKET_SHIFT;

    // ---- try cooperative mega-kernel with runtime-verified co-residency ----
    bool coop_done = false;
    int dev = 0;
    (void)hipGetDevice(&dev);
    int blocksPerCU = 0, numCU = 0;
    hipError_t e1 = hipOccupancyMaxActiveBlocksPerMultiprocessor(
        &blocksPerCU, gat_mega, 256, 0);
    hipError_t e2 = hipDeviceGetAttribute(
        &numCU, hipDeviceAttributeMultiprocessorCount, dev);
    if (e1 == hipSuccess && e2 == hipSuccess && blocksPerCU >= 1 && numCU >= 1) {
        int G = blocksPerCU * numCU;
        if (G > 2048) G = 2048;
        int chunkE = (E + G - 1) / G;
        int M = NB * G;
        int nch2 = (M + SC - 1) / SC;

        char* w = (char*)d_ws;
        float4* h2p  = (float4*)w;  w += (size_t)N * sizeof(float4);
        float*  as1  = (float*)w;   w += (size_t)N * 2 * sizeof(float);
        float*  ad1  = (float*)w;   w += (size_t)N * 2 * sizeof(float);
        float*  ad2  = (float*)w;   w += (size_t)N * sizeof(float);
        int* rp     = (int*)w;      w += (size_t)(N + 4) * sizeof(int);
        int* cmatT  = (int*)w;      w += (size_t)M * sizeof(int);
        int* cscan  = (int*)w;      w += (size_t)M * sizeof(int);
        int* bsum   = (int*)w;      w += (size_t)(nch2 + 8) * sizeof(int);
        int* bscan  = (int*)w;      w += (size_t)(nch2 + 8) * sizeof(int);
        unsigned int* ebuf = (unsigned int*)w;  w += (size_t)E * sizeof(unsigned int);
        int* esrt   = (int*)w;      w += (size_t)E * sizeof(int);

        void* args[] = { &x, &srcp, &dstp, &W1, &a_src1, &a_dst1, &b1, &W2,
                         &a_src2, &a_dst2, &b2, &out, &as1, &ad1, &ad2, &h2p,
                         &rp, &cmatT, &cscan, &bsum, &bscan, &ebuf, &esrt,
                         &N, &E, &NB, &nch2, &chunkE };
        hipError_t err = hipLaunchCooperativeKernel(
            (void*)gat_mega, dim3(G), dim3(256), args, 0, stream);
        coop_done = (err == hipSuccess);
    }
    if (coop_done) return;

    // ---- fallback: round-13 multi-kernel pipeline (measured 182.6 us) ------
    const int nblkE = (E + EB_CHUNK - 1) / EB_CHUNK;
    const int M     = NB * nblkE;
    const int nb2   = (M + SC - 1) / SC;

    char* w = (char*)d_ws;
    float4* h2p  = (float4*)w;  w += (size_t)N * sizeof(float4);
    float*  as1  = (float*)w;   w += (size_t)N * 2 * sizeof(float);
    float*  ad1  = (float*)w;   w += (size_t)N * 2 * sizeof(float);
    float*  ad2  = (float*)w;   w += (size_t)N * sizeof(float);
    int* rp     = (int*)w;      w += (size_t)(N + 4) * sizeof(int);
    int* cmatT  = (int*)w;      w += (size_t)M * sizeof(int);
    int* cscan  = (int*)w;      w += (size_t)M * sizeof(int);
    int* bsum   = (int*)w;      w += (size_t)(nb2 + 4) * sizeof(int);
    int* bscan  = (int*)w;      w += (size_t)(nb2 + 4) * sizeof(int);
    unsigned int* ebuf = (unsigned int*)w;  w += (size_t)E * sizeof(unsigned int);
    int* esrt   = (int*)w;      w += (size_t)E * sizeof(int);

    const int BT = 256;
    k0_prep1<<<((size_t)N * 32 + BT - 1) / BT, BT, 0, stream>>>(
        x, W1, a_src1, a_dst1, as1, ad1, N);
    p1_hist<<<nblkE, 256, 0, stream>>>(dstp, cmatT, E, NB, nblkE);
    k2a_partials<<<nb2, 256, 0, stream>>>(cmatT, bsum, M);
    k2b_scanb<<<1, 1024, 0, stream>>>(bsum, bscan, nb2);
    k2c_scan<<<nb2, 256, 0, stream>>>(cmatT, bscan, cscan, M);
    p3_scatter<<<nblkE, 256, 0, stream>>>(srcp, dstp, cscan, ebuf, E, NB, nblkE);
    p4_csr<<<NB, 256, 0, stream>>>(ebuf, cscan, rp, esrt, N, E, NB, nblkE);
    k4_layer1<<<((size_t)N * 8 + BT - 1) / BT, BT, 0, stream>>>(
        rp, esrt, x, as1, ad1, b1, W1, W2, a_src2, a_dst2, h2p, ad2, N);
    k5_layer2<<<((size_t)N * 8 + BT - 1) / BT, BT, 0, stream>>>(
        rp, esrt, h2p, ad2, b2, out, N);
}